// Round 1
// baseline (5642.694 us; speedup 1.0000x reference)
//
#include <hip/hip_runtime.h>
#include <cmath>

static constexpr int Bn = 128;
static constexpr int Nn = 256;
static constexpr int META_PB = 131072;   // per-batch metadata bytes (uint8)

// ---------------------------------------------------------------------------
// Kernel 1: z = logits - log(-log(clip(u))), zero arb, init f64/f32 score
// matrix M[b][i][j] (stride 256) with diag & column-0 = -inf.
// Region i,j >= L is never read by the solver (loops bounded by current size),
// so no length masking needed here.
// ---------------------------------------------------------------------------
template <typename T>
__global__ __launch_bounds__(256) void zinit_kernel(
    const float* __restrict__ logits,
    const float* __restrict__ u,
    float* __restrict__ zout,
    float* __restrict__ arb,
    T* __restrict__ M)
{
    int idx = blockIdx.x * blockDim.x + threadIdx.x;   // < Bn*Nn*Nn
    int j = idx & (Nn - 1);
    int i = (idx >> 8) & (Nn - 1);
    const float EPS = 1.1920928955078125e-07f;         // float32 eps
    float uv = u[idx];
    uv = fminf(fmaxf(uv, EPS), 1.0f - EPS);
    float z = logits[idx] - logf(-logf(uv));
    zout[idx] = z;
    arb[idx] = 0.0f;
    M[idx] = (i == j || j == 0) ? (T)(-INFINITY) : (T)z;
}

// ---------------------------------------------------------------------------
// Kernel 2: per-batch Chu-Liu/Edmonds, literal port of the reference
// recursion (iterative: contract loop + metadata stack + unwind).
// One block (256 threads) per batch element.
// ---------------------------------------------------------------------------
template <typename T>
__global__ __launch_bounds__(256) void edmonds_kernel(
    const int* __restrict__ lengths,
    const float* __restrict__ zout,
    T* __restrict__ Mg,
    unsigned char* __restrict__ metag,
    float* __restrict__ arb,
    float* __restrict__ stats)
{
    const int b = blockIdx.x;
    const int t = threadIdx.x;
    T* M = Mg + (size_t)b * (Nn * Nn);
    unsigned char* meta = metag + (size_t)b * META_PB;
    const float* zb = zout + (size_t)b * (Nn * Nn);

    __shared__ unsigned short heads[256];
    __shared__ unsigned short h2[256];
    __shared__ unsigned char color[256];
    __shared__ unsigned short path[256];
    __shared__ unsigned short cyc[256];
    __shared__ unsigned short non[256];
    __shared__ unsigned char argin[256];
    __shared__ unsigned char argout[256];
    __shared__ T chs[256];
    __shared__ T vin[256];
    __shared__ T vout[256];
    __shared__ double red[256];
    __shared__ unsigned short lev_n[256];
    __shared__ unsigned short lev_c[256];
    __shared__ int lev_off[256];
    __shared__ int sh_clen;
    __shared__ int sh_n;

    const int L = lengths[b];
    int Lc = L;
    int depth = 0;
    int moff = 0;

    while (true) {
        // ---- heads = argmax over rows for each column (first max) ----
        if (t < Lc) {
            T best = -INFINITY; int bi = 0;
            for (int i = 0; i < Lc; ++i) {
                T v = M[i * Nn + t];              // coalesced across t
                if (v > best) { best = v; bi = i; }
            }
            heads[t] = (unsigned short)bi;
        }
        __syncthreads();

        // ---- cycle detection (exact reference order), thread 0 ----
        if (t == 0) {
            heads[0] = 0;
            for (int i = 0; i < Lc; ++i) color[i] = 0;
            color[0] = 2;
            int clen = 0;
            for (int start = 1; start < Lc; ++start) {
                if (color[start]) continue;
                int plen = 0;
                int v = start;
                while (color[v] == 0) {
                    color[v] = 1;
                    path[plen++] = (unsigned short)v;
                    v = heads[v];
                }
                if (color[v] == 1) {
                    int i0 = 0;
                    while (path[i0] != v) ++i0;
                    clen = plen - i0;
                    for (int k = 0; k < clen; ++k) cyc[k] = path[i0 + k];
                    break;
                }
                for (int k = 0; k < plen; ++k) color[path[k]] = 2;
            }
            sh_clen = clen;
            if (clen) {
                // non = sorted complement of cyc
                for (int i = 0; i < Lc; ++i) color[i] = 1;
                for (int k = 0; k < clen; ++k) color[cyc[k]] = 0;
                int n = 0;
                for (int i = 0; i < Lc; ++i) if (color[i]) non[n++] = (unsigned short)i;
                sh_n = n;
            }
        }
        __syncthreads();
        const int clen = sh_clen;
        if (clen == 0) break;                    // heads[] = solution at this level
        const int n = sh_n;

        // ---- cyc_head_sc ----
        if (t < clen) chs[t] = M[(int)heads[cyc[t]] * Nn + cyc[t]];
        __syncthreads();

        // ---- into: per non-row, first-max over cyc of (score - chs) ----
        if (t < n) {
            const int r = non[t];
            T best = -INFINITY; int bi = 0;
            for (int c = 0; c < clen; ++c) {
                T v = M[r * Nn + cyc[c]] - chs[c];
                if (v > best) { best = v; bi = c; }
            }
            vin[t] = best; argin[t] = (unsigned char)bi;
        }
        // ---- outo: per non-col, first-max over cyc rows (no subtraction) ----
        if (t < n) {
            const int cj = non[t];
            T best = -INFINITY; int bi = 0;
            for (int c = 0; c < clen; ++c) {
                T v = M[(int)cyc[c] * Nn + cj];  // coalesced across t
                if (v > best) { best = v; bi = c; }
            }
            vout[t] = best; argout[t] = (unsigned char)bi;
        }
        __syncthreads();

        // ---- push level metadata: non[n] argin[n] argout[n] cyc[c] headscyc[c]
        unsigned char* mp = meta + moff;
        if (t < n) {
            mp[t] = (unsigned char)non[t];
            mp[n + t] = argin[t];
            mp[2 * n + t] = argout[t];
        }
        if (t < clen) {
            mp[3 * n + t] = (unsigned char)cyc[t];
            mp[3 * n + clen + t] = (unsigned char)heads[cyc[t]];
        }
        if (t == 0) {
            lev_n[depth] = (unsigned short)n;
            lev_c[depth] = (unsigned short)clen;
            lev_off[depth] = moff;
        }
        moff += 3 * n + 2 * clen;
        ++depth;
        __syncthreads();

        // ---- in-place compaction: new[i][j] = old[non[i]][non[j]] ----
        // Safe because non[k] >= k: row i is never a future source row.
        for (int i = 0; i < n; ++i) {
            T v = (T)0;
            const int src = non[i];
            if (t < n) v = M[src * Nn + non[t]];
            __syncthreads();
            if (t < n) M[i * Nn + t] = v;
            if (t == 0) M[i * Nn + n] = vin[i];
            __syncthreads();
        }
        if (t < n) M[n * Nn + t] = vout[t];
        if (t == 0) M[n * Nn + n] = (T)(-INFINITY);
        __syncthreads();

        Lc = n + 1;
    }

    // ---- unwind ----
    unsigned short* hcur = heads;
    unsigned short* hnew = h2;
    for (int lvl = depth - 1; lvl >= 0; --lvl) {
        const int n = lev_n[lvl];
        const int c = lev_c[lvl];
        const unsigned char* mp = meta + lev_off[lvl];
        const unsigned char* pnon   = mp;
        const unsigned char* pargin = mp + n;
        const unsigned char* pargout= mp + 2 * n;
        const unsigned char* pcyc   = mp + 3 * n;
        const unsigned char* phcyc  = mp + 3 * n + c;
        if (t < n) {
            const int x = hcur[t];
            hnew[pnon[t]] = (x == n) ? (unsigned short)pcyc[pargout[t]]
                                     : (unsigned short)pnon[x];
        }
        if (t < c) hnew[pcyc[t]] = phcyc[t];
        __syncthreads();
        if (t == 0) {
            const int hc = hcur[n];
            hnew[pcyc[pargin[hc]]] = pnon[hc];
            hnew[0] = 0;
        }
        __syncthreads();
        unsigned short* tmp = hcur; hcur = hnew; hnew = tmp;
    }

    // ---- emit arb (ones) and stats ----
    double acc = 0.0;
    if (t >= 1 && t < L) {
        const int h = hcur[t];
        arb[(size_t)b * (Nn * Nn) + h * Nn + t] = 1.0f;
        acc = (double)zb[h * Nn + t];
    }
    red[t] = acc;
    __syncthreads();
    for (int s = 128; s > 0; s >>= 1) {
        if (t < s) red[t] += red[t + s];
        __syncthreads();
    }
    if (t == 0) stats[b] = (float)red[0];
}

// ---------------------------------------------------------------------------
extern "C" void kernel_launch(void* const* d_in, const int* in_sizes, int n_in,
                              void* d_out, int out_size, void* d_ws, size_t ws_size,
                              hipStream_t stream)
{
    const float* logits  = (const float*)d_in[0];
    const float* u       = (const float*)d_in[1];
    const int*   lengths = (const int*)d_in[2];

    float* out   = (float*)d_out;
    float* arb   = out;                                  // Bn*Nn*Nn
    float* stats = out + (size_t)Bn * Nn * Nn;           // Bn
    float* zout  = stats + Bn;                           // Bn*Nn*Nn

    const int total = Bn * Nn * Nn;
    const int zblocks = total / 256;

    const size_t needD = (size_t)Bn * Nn * Nn * sizeof(double) + (size_t)Bn * META_PB;

    if (ws_size >= needD) {
        double* M = (double*)d_ws;
        unsigned char* meta = (unsigned char*)d_ws + (size_t)Bn * Nn * Nn * sizeof(double);
        zinit_kernel<double><<<zblocks, 256, 0, stream>>>(logits, u, zout, arb, M);
        edmonds_kernel<double><<<Bn, 256, 0, stream>>>(lengths, zout, M, meta, arb, stats);
    } else {
        // fallback: f32 score matrices (tiny risk of ulp-level argmax flips)
        float* M = (float*)d_ws;
        unsigned char* meta = (unsigned char*)d_ws + (size_t)Bn * Nn * Nn * sizeof(float);
        zinit_kernel<float><<<zblocks, 256, 0, stream>>>(logits, u, zout, arb, M);
        edmonds_kernel<float><<<Bn, 256, 0, stream>>>(lengths, zout, M, meta, arb, stats);
    }
}

// Round 2
// 853.586 us; speedup vs baseline: 6.6106x; 6.6106x over previous
//
#include <hip/hip_runtime.h>
#include <cmath>

static constexpr int Bn = 128;
static constexpr int Nn = 256;
static constexpr int META_PB = 131072;   // per-batch metadata bytes (uint8)

// ---------------------------------------------------------------------------
// Kernel 1: z = logits - log(-log(clip(u))), zero arb, init score matrix
// M[b][i][j] (stride 256) with diag & column-0 = -inf.
// ---------------------------------------------------------------------------
template <typename T>
__global__ __launch_bounds__(256) void zinit_kernel(
    const float* __restrict__ logits,
    const float* __restrict__ u,
    float* __restrict__ zout,
    float* __restrict__ arb,
    T* __restrict__ M)
{
    int idx = blockIdx.x * blockDim.x + threadIdx.x;   // < Bn*Nn*Nn
    int j = idx & (Nn - 1);
    int i = (idx >> 8) & (Nn - 1);
    const float EPS = 1.1920928955078125e-07f;         // float32 eps
    float uv = u[idx];
    uv = fminf(fmaxf(uv, EPS), 1.0f - EPS);
    float z = logits[idx] - logf(-logf(uv));
    zout[idx] = z;
    arb[idx] = 0.0f;
    M[idx] = (i == j || j == 0) ? (T)(-INFINITY) : (T)z;
}

// ---------------------------------------------------------------------------
// Kernel 2: per-batch Chu-Liu/Edmonds with in-place supernode contraction
// (active-slot indirection, incremental argmax maintenance, pointer-doubling
// cycle detection). One block (256 threads) per batch element.
// ---------------------------------------------------------------------------
template <typename T>
__global__ __launch_bounds__(256) void edmonds_kernel(
    const int* __restrict__ lengths,
    const float* __restrict__ zout,
    T* __restrict__ Mg,
    unsigned char* __restrict__ metag,
    float* __restrict__ arb,
    float* __restrict__ stats)
{
    const int b = blockIdx.x;
    const int t = threadIdx.x;
    T* M = Mg + (size_t)b * (Nn * Nn);
    unsigned char* meta = metag + (size_t)b * META_PB;
    const float* zb = zout + (size_t)b * (Nn * Nn);

    __shared__ unsigned short act[256];   // compact index -> original slot
    __shared__ unsigned short h[256];     // compact heads
    __shared__ unsigned short h2[256];    // scratch / unwind ping-pong
    __shared__ unsigned short p[256];     // pointer doubling
    __shared__ unsigned short inv_[256];  // old compact -> new compact (survivors)
    __shared__ unsigned short cyc_c[256];
    __shared__ unsigned short non_c[256];
    __shared__ unsigned short lev_n[256], lev_c[256], resc[256];
    __shared__ int lev_off[256];
    __shared__ unsigned char in_cyc[256], argin[256], argout[256];
    __shared__ T hval[256];               // per-column current max value
    __shared__ T vin[256], vout[256], chs[256];
    __shared__ double red[256];
    __shared__ int wcnt[4];
    __shared__ int sh_clen, sh_cnt, sh_wslot;

    const int L = lengths[b];
    const int lane = t & 63, wv = t >> 6;

    act[t] = (unsigned short)t;
    // ---- initial full column argmax (first-max) ----
    if (t < L) {
        T best = -INFINITY; int bi = 0;
        const T* col = M + t;
        for (int i = 0; i < L; ++i) {
            T v = col[i * Nn];                 // coalesced across t
            if (v > best) { best = v; bi = i; }
        }
        h[t] = (t == 0) ? (unsigned short)0 : (unsigned short)bi;
        hval[t] = best;
    }
    __syncthreads();

    int Lc = L, depth = 0, moff = 0;

    while (true) {
        // ---- cycle existence via pointer doubling: p = heads^(256) ----
        if (t < Lc) p[t] = h[t];
        __syncthreads();
        for (int r = 0; r < 8; ++r) {
            unsigned short np_ = 0;
            if (t < Lc) np_ = p[p[t]];
            __syncthreads();
            if (t < Lc) p[t] = np_;
            __syncthreads();
        }
        // min v>=1 whose chain ends on a non-root cycle (matches reference's
        // first-found cycle: first start index that reaches a cycle)
        h2[t] = (t >= 1 && t < Lc && p[t] != 0) ? (unsigned short)t
                                                : (unsigned short)0xFFFF;
        __syncthreads();
        for (int s = 128; s > 0; s >>= 1) {
            if (t < s) { if (h2[t + s] < h2[t]) h2[t] = h2[t + s]; }
            __syncthreads();
        }
        const int vstar = h2[0];
        __syncthreads();
        if (vstar == 0xFFFF) break;            // no cycle: h[] is the solution

        // ---- enumerate the cycle (small serial walk, length = clen) ----
        in_cyc[t] = 0;
        __syncthreads();
        if (t == 0) {
            int w = p[vstar];                  // a node ON the cycle
            int cl = 0, v = w;
            do { cyc_c[cl++] = (unsigned short)v; in_cyc[v] = 1; v = h[v]; }
            while (v != w);
            sh_clen = cl;
            sh_wslot = act[w];
        }
        __syncthreads();
        const int clen = sh_clen;
        const int n = Lc - clen;
        const int wslot = sh_wslot;

        // ---- non list: order-preserving compaction via ballot prefix ----
        const bool fl = (t < Lc) && !in_cyc[t];
        unsigned long long mask = __ballot(fl);
        if (lane == 0) wcnt[wv] = __popcll(mask);
        __syncthreads();
        if (fl) {
            int base = 0;
            for (int k = 0; k < wv; ++k) base += wcnt[k];
            int pos = base + __popcll(mask & ((1ull << lane) - 1ull));
            non_c[pos] = (unsigned short)t;
            inv_[t] = (unsigned short)pos;
        }
        if (t < clen) chs[t] = hval[cyc_c[t]]; // = M[heads[cyc]][cyc]
        __syncthreads();

        // ---- into (score - chs, max over cyc) and outo (max over cyc rows) ----
        if (t < n) {
            const int slot = act[non_c[t]];
            T bv = -INFINITY; int bi = 0;
            for (int c = 0; c < clen; ++c) {
                T v = M[slot * Nn + (int)act[cyc_c[c]]] - chs[c];
                if (v > bv) { bv = v; bi = c; }
            }
            vin[t] = bv; argin[t] = (unsigned char)bi;
            T bo = -INFINITY; int bj = 0;
            for (int c = 0; c < clen; ++c) {
                T v = M[(int)act[cyc_c[c]] * Nn + slot];
                if (v > bo) { bo = v; bj = c; }
            }
            vout[t] = bo; argout[t] = (unsigned char)bj;
        }
        __syncthreads();

        // ---- meta push + supernode row/col writes + capture remap values ----
        unsigned char* mp = meta + moff;
        if (t < n) {
            mp[t] = (unsigned char)non_c[t];
            mp[n + t] = argin[t];
            mp[2 * n + t] = argout[t];
            M[(int)act[non_c[t]] * Nn + wslot] = vin[t];   // new column n
            M[wslot * Nn + (int)act[non_c[t]]] = vout[t];  // new row n
        }
        if (t < clen) {
            mp[3 * n + t] = (unsigned char)cyc_c[t];
            mp[3 * n + clen + t] = (unsigned char)h[cyc_c[t]];
        }
        if (t == 0) {
            M[wslot * Nn + wslot] = (T)(-INFINITY);
            lev_n[depth] = (unsigned short)n;
            lev_c[depth] = (unsigned short)clen;
            lev_off[depth] = moff;
            sh_cnt = 0;
        }
        // capture (reads of old act/h/hval before they are overwritten)
        unsigned short myact = 0, myh = 0; T myhval = (T)0; bool need = false;
        if (t < n) {
            const int oc = non_c[t];
            myact = act[oc];
            const int ho = h[oc];
            if (in_cyc[ho]) need = true;       // head got contracted: rescan
            else { myh = inv_[ho]; myhval = hval[oc]; }
        }
        __syncthreads();

        // ---- remap to new compact space ----
        if (t < n) {
            act[t] = myact;
            if (!need) { h[t] = myh; hval[t] = myhval; }
            else { int k = atomicAdd(&sh_cnt, 1); resc[k] = (unsigned short)t; }
        }
        if (t == 0) {
            act[n] = (unsigned short)wslot;
            int k = atomicAdd(&sh_cnt, 1); resc[k] = (unsigned short)n; // supernode col
        }
        __syncthreads();
        moff += 3 * n + 2 * clen;
        ++depth;
        Lc = n + 1;

        // ---- rescan the few invalidated columns (first-max over new rows) ----
        const int nr = sh_cnt;
        if (t < nr) {
            const int jc = resc[t];
            const int cslot = act[jc];
            T best = -INFINITY; int bi = 0;
            for (int i = 0; i < Lc; ++i) {
                T v = M[(int)act[i] * Nn + cslot];
                if (v > best) { best = v; bi = i; }
            }
            h[jc] = (unsigned short)bi;
            hval[jc] = best;
        }
        if (t == 0) h[0] = 0;
        __syncthreads();
    }

    // ---- unwind (identical to the verified round-1 logic) ----
    unsigned short* hcur = h;
    unsigned short* hnew = h2;
    for (int lvl = depth - 1; lvl >= 0; --lvl) {
        const int n = lev_n[lvl];
        const int c = lev_c[lvl];
        const unsigned char* mp = meta + lev_off[lvl];
        const unsigned char* pnon    = mp;
        const unsigned char* pargin  = mp + n;
        const unsigned char* pargout = mp + 2 * n;
        const unsigned char* pcyc    = mp + 3 * n;
        const unsigned char* phcyc   = mp + 3 * n + c;
        if (t < n) {
            const int x = hcur[t];
            hnew[pnon[t]] = (x == n) ? (unsigned short)pcyc[pargout[t]]
                                     : (unsigned short)pnon[x];
        }
        if (t < c) hnew[pcyc[t]] = phcyc[t];
        __syncthreads();
        if (t == 0) {
            const int hc = hcur[n];
            hnew[pcyc[pargin[hc]]] = pnon[hc];
            hnew[0] = 0;
        }
        __syncthreads();
        unsigned short* tmp = hcur; hcur = hnew; hnew = tmp;
    }

    // ---- emit arb (ones) and stats ----
    double acc = 0.0;
    if (t >= 1 && t < L) {
        const int hd = hcur[t];
        arb[(size_t)b * (Nn * Nn) + hd * Nn + t] = 1.0f;
        acc = (double)zb[hd * Nn + t];
    }
    red[t] = acc;
    __syncthreads();
    for (int s = 128; s > 0; s >>= 1) {
        if (t < s) red[t] += red[t + s];
        __syncthreads();
    }
    if (t == 0) stats[b] = (float)red[0];
}

// ---------------------------------------------------------------------------
extern "C" void kernel_launch(void* const* d_in, const int* in_sizes, int n_in,
                              void* d_out, int out_size, void* d_ws, size_t ws_size,
                              hipStream_t stream)
{
    const float* logits  = (const float*)d_in[0];
    const float* u       = (const float*)d_in[1];
    const int*   lengths = (const int*)d_in[2];

    float* out   = (float*)d_out;
    float* arb   = out;                                  // Bn*Nn*Nn
    float* stats = out + (size_t)Bn * Nn * Nn;           // Bn
    float* zout  = stats + Bn;                           // Bn*Nn*Nn

    const int total = Bn * Nn * Nn;
    const int zblocks = total / 256;

    const size_t needD = (size_t)Bn * Nn * Nn * sizeof(double) + (size_t)Bn * META_PB;

    if (ws_size >= needD) {
        double* M = (double*)d_ws;
        unsigned char* meta = (unsigned char*)d_ws + (size_t)Bn * Nn * Nn * sizeof(double);
        zinit_kernel<double><<<zblocks, 256, 0, stream>>>(logits, u, zout, arb, M);
        edmonds_kernel<double><<<Bn, 256, 0, stream>>>(lengths, zout, M, meta, arb, stats);
    } else {
        // fallback: f32 score matrices (tiny risk of ulp-level argmax flips)
        float* M = (float*)d_ws;
        unsigned char* meta = (unsigned char*)d_ws + (size_t)Bn * Nn * Nn * sizeof(float);
        zinit_kernel<float><<<zblocks, 256, 0, stream>>>(logits, u, zout, arb, M);
        edmonds_kernel<float><<<Bn, 256, 0, stream>>>(lengths, zout, M, meta, arb, stats);
    }
}